// Round 13
// baseline (240.441 us; speedup 1.0000x reference)
//
#include <hip/hip_runtime.h>
#include <hip/hip_fp8.h>
#include <math.h>

#define N_NODES 50000
#define N_EDGES 800000
#define NP 8                      // node partitions (6250 nodes each)
#define NS 64                     // edge segments (12500 edges each)
#define PSZ (N_NODES / NP)        // 6250
#define SSZ (N_EDGES / NS)        // 12500
#define NB 196                    // ceil(N/256)

typedef _Float16 half8 __attribute__((ext_vector_type(8)));
typedef float floatx4 __attribute__((ext_vector_type(4)));

// ---------------- fp8 e4m3 (OCP) helpers — HW cvt on gfx950 ----------------
__device__ __forceinline__ unsigned char f_to_fp8(float f) {
    __hip_fp8_e4m3 q(f);
    return (unsigned char)q.__x;
}
__device__ __forceinline__ float fp8_to_f(unsigned char u) {
    __hip_fp8_e4m3 q;
    q.__x = (__hip_fp8_storage_t)u;
    return (float)q;
}

// ---------------------------------------------------------------------------
// Fused: partitioned LDS histogram (blocks 0..NP*NS-1) + WT transpose +
// gacc/gcnt zeroing. Histogram packs BOTH counters in one u32: in-degree in
// low 16 bits (+1), out-degree in high 16 (+0x10000) — per-segment counts
// <= ~12, no carry. LDS = 25 KB/block. The atomicAdd return's low 16 bits
// IS the edge's within-segment rank (u8 store) — csr_fill needs no atomics.
// NS=64 => 512 hist blocks => 2 blocks/CU, whole GPU busy.
// ---------------------------------------------------------------------------
__global__ __launch_bounds__(256) void hist_wt_kernel(const int* __restrict__ src,
                                                      const int* __restrict__ dst,
                                                      unsigned char* __restrict__ inpart,
                                                      unsigned char* __restrict__ outpart,
                                                      unsigned char* __restrict__ rank,
                                                      const float* __restrict__ W2,
                                                      const float* __restrict__ W3,
                                                      const float* __restrict__ W4,
                                                      _Float16* __restrict__ WT,
                                                      float* __restrict__ gacc) {
    __shared__ int h[PSZ + 2];                   // pad to int4 multiple (6252)
    if (blockIdx.x >= NP * NS) {
        int wb = blockIdx.x - NP * NS;
        if (wb < 48) {                           // WT transpose: f32 [k][n] -> f16 [n][k]
            int i = wb * 256 + threadIdx.x;
            if (i < 3 * 4096) {
                int l = i >> 12;
                int r = i & 4095;
                int k = r >> 6, n = r & 63;
                const float* W = (l == 0) ? W2 : (l == 1) ? W3 : W4;
                WT[l * 4096 + n * 64 + k] = (_Float16)W[r];
            }
        } else {                                 // zero gacc[4096] + gcnt[64]
            for (int i = threadIdx.x; i < 64 * 64 + 64; i += 256) gacc[i] = 0.0f;
        }
        return;
    }
    int p = blockIdx.x / NS, s = blockIdx.x % NS;
    for (int i = threadIdx.x; i < (PSZ + 2) / 4 + 1; i += 256)
        if (4 * i < PSZ + 2) ((int4*)h)[i] = make_int4(0, 0, 0, 0);
    __syncthreads();
    int lo = p * PSZ;
    int ebase = s * SSZ;
    const int4* d4 = (const int4*)(dst + ebase);
    const int4* s4 = (const int4*)(src + ebase);
    unsigned char* rk = rank + ebase;
    for (int i = threadIdx.x; i < SSZ / 4; i += 256) {
        int4 d = d4[i];
        int4 sv = s4[i];
        int t;
        t = d.x - lo;  if ((unsigned)t < PSZ) rk[4 * i + 0] = (unsigned char)(atomicAdd(&h[t], 1) & 0xffff);
        t = d.y - lo;  if ((unsigned)t < PSZ) rk[4 * i + 1] = (unsigned char)(atomicAdd(&h[t], 1) & 0xffff);
        t = d.z - lo;  if ((unsigned)t < PSZ) rk[4 * i + 2] = (unsigned char)(atomicAdd(&h[t], 1) & 0xffff);
        t = d.w - lo;  if ((unsigned)t < PSZ) rk[4 * i + 3] = (unsigned char)(atomicAdd(&h[t], 1) & 0xffff);
        t = sv.x - lo; if ((unsigned)t < PSZ) atomicAdd(&h[t], 0x10000);
        t = sv.y - lo; if ((unsigned)t < PSZ) atomicAdd(&h[t], 0x10000);
        t = sv.z - lo; if ((unsigned)t < PSZ) atomicAdd(&h[t], 0x10000);
        t = sv.w - lo; if ((unsigned)t < PSZ) atomicAdd(&h[t], 0x10000);
    }
    __syncthreads();
    // write-out: uchar2 (offsets s*N + p*PSZ are even => 2B-aligned)
    unsigned char* ip = inpart + (size_t)s * N_NODES + lo;
    unsigned char* op = outpart + (size_t)s * N_NODES + lo;
    for (int i = threadIdx.x; i < PSZ / 2; i += 256) {
        int v0 = h[2 * i], v1 = h[2 * i + 1];
        uchar2 iv, ov;
        iv.x = (unsigned char)(v0 & 0xff);
        iv.y = (unsigned char)(v1 & 0xff);
        ov.x = (unsigned char)((v0 >> 16) & 0xff);
        ov.y = (unsigned char)((v1 >> 16) & 0xff);
        ((uchar2*)ip)[i] = iv;
        ((uchar2*)op)[i] = ov;
    }
}

// ---------------------------------------------------------------------------
// Fused: reduce u8 segment partials -> degrees, features/norms, block scan,
// AND per-graph node counts (LDS histogram, 64 atomics per block).
// ---------------------------------------------------------------------------
__global__ void scan_block_feat_kernel(const unsigned char* __restrict__ inpart,
                                       const unsigned char* __restrict__ outpart,
                                       const int* __restrict__ graph_ids,
                                       int* __restrict__ row_start, int* __restrict__ blk_sums,
                                       float* __restrict__ norm_src, float* __restrict__ norm_dst,
                                       float4* __restrict__ hs0, float* __restrict__ gcnt, int N) {
    __shared__ int ghist[64];
    if (threadIdx.x < 64) ghist[threadIdx.x] = 0;
    int i = blockIdx.x * 256 + threadIdx.x;
    int din_i = 0, dout_i = 0;
    if (i < N) {
#pragma unroll
        for (int s = 0; s < NS; ++s) {
            din_i += inpart[(size_t)s * N_NODES + i];
            dout_i += outpart[(size_t)s * N_NODES + i];
        }
        float din = (float)din_i;
        float dout = (float)dout_i;
        float ns = 1.0f / sqrtf(fmaxf(dout, 1.0f));
        float nd = 1.0f / sqrtf(fmaxf(din, 1.0f));
        norm_src[i] = ns;
        norm_dst[i] = nd;
        float h1 = din;
        float h2 = (din - 3.0f > 0.0f) ? 1.0f : 0.0f;
        float h3 = 3.0f / din;
        float h4 = (din - 4.0f > 0.0f) ? 1.0f : 0.0f;
        hs0[i] = make_float4(h1 * ns, h2 * ns, h3 * ns, h4 * ns);
    }
    __syncthreads();
    if (i < N) atomicAdd(&ghist[graph_ids[i]], 1);
    int lane = threadIdx.x & 63;
    int wid = threadIdx.x >> 6;
    int x = din_i;
#pragma unroll
    for (int off = 1; off < 64; off <<= 1) {
        int t = __shfl_up(x, off);
        if (lane >= off) x += t;
    }
    __shared__ int wsum[4];
    if (lane == 63) wsum[wid] = x;
    __syncthreads();
    int woff = 0;
    for (int w = 0; w < wid; ++w) woff += wsum[w];
    int incl = x + woff;
    if (i < N) row_start[i] = incl - din_i;
    if (threadIdx.x == 255) blk_sums[blockIdx.x] = incl;
    if (threadIdx.x < 64 && ghist[threadIdx.x] > 0)
        atomicAdd(&gcnt[threadIdx.x], (float)ghist[threadIdx.x]);
}

// ---------------------------------------------------------------------------
// Finalize row_start (each block re-scans the 196 block sums locally) and
// rewrite inpart[s][i] in place into the exclusive within-row prefix.
// ---------------------------------------------------------------------------
__global__ void scan_add_prefix_kernel(int* __restrict__ row_start,
                                       const int* __restrict__ blk_sums,
                                       unsigned char* __restrict__ inpart, int N) {
    __shared__ int sOff[256];
    int t = threadIdx.x;
    int v = (t < NB) ? blk_sums[t] : 0;
    int lane = t & 63;
    int wid = t >> 6;
    int x = v;
#pragma unroll
    for (int off = 1; off < 64; off <<= 1) {
        int tt = __shfl_up(x, off);
        if (lane >= off) x += tt;
    }
    __shared__ int wsum[4];
    if (lane == 63) wsum[wid] = x;
    __syncthreads();
    int woff = 0;
    for (int w = 0; w < wid; ++w) woff += wsum[w];
    sOff[t] = x + woff - v;              // exclusive prefix of blk_sums
    __syncthreads();
    int blockOff = sOff[blockIdx.x];

    int i = blockIdx.x * 256 + threadIdx.x;
    if (blockIdx.x == 0 && threadIdx.x == 0) row_start[N] = N_EDGES;
    if (i >= N) return;
    row_start[i] += blockOff;
    unsigned char run = 0;
#pragma unroll
    for (int s = 0; s < NS; ++s) {
        unsigned char c = inpart[(size_t)s * N_NODES + i];
        inpart[(size_t)s * N_NODES + i] = run;
        run = (unsigned char)(run + c);
    }
}

// ---------------------------------------------------------------------------
// Rank-based CSR fill: pos = row_start[d] + pref[s][d] + rank[e].
// No atomics, no LDS, grid-stride, fully parallel.
// ---------------------------------------------------------------------------
__global__ __launch_bounds__(256) void csr_fill_kernel(const int* __restrict__ src,
                                                       const int* __restrict__ dst,
                                                       const int* __restrict__ row_start,
                                                       const unsigned char* __restrict__ inpart,
                                                       const unsigned char* __restrict__ rank,
                                                       int* __restrict__ csr_src) {
    int i = blockIdx.x * 256 + threadIdx.x;          // edge-quad index
    if (i >= N_EDGES / 4) return;
    int4 d = ((const int4*)dst)[i];
    int4 sv = ((const int4*)src)[i];
    uchar4 rk = ((const uchar4*)rank)[i];
    int s = (4 * i) / SSZ;                           // uniform per SSZ/4 quads
    const unsigned char* pref = inpart + (size_t)s * N_NODES;
    csr_src[row_start[d.x] + (int)pref[d.x] + (int)rk.x] = sv.x;
    csr_src[row_start[d.y] + (int)pref[d.y] + (int)rk.y] = sv.y;
    csr_src[row_start[d.z] + (int)pref[d.z] + (int)rk.z] = sv.z;
    csr_src[row_start[d.w] + (int)pref[d.w] + (int)rk.w] = sv.w;
}

// ---------------------------------------------------------------------------
// Layer 1: IN=4 -> H=64. One wave per node; lanes split neighbors.
// Output fp8 (layer-2 gather input), pre-scaled by norm_src.
// ---------------------------------------------------------------------------
__global__ void conv4_kernel(const float4* __restrict__ hs0,
                             const int* __restrict__ row_start,
                             const int* __restrict__ csr_src,
                             const float* __restrict__ norm_src,
                             const float* __restrict__ norm_dst,
                             const float* __restrict__ W, const float* __restrict__ b,
                             unsigned char* __restrict__ out, int N) {
    __shared__ float sW[4 * 64];
    __shared__ float sb[64];
    sW[threadIdx.x] = W[threadIdx.x];
    if (threadIdx.x < 64) sb[threadIdx.x] = b[threadIdx.x];
    __syncthreads();
    int lane = threadIdx.x & 63;
    int wid = threadIdx.x >> 6;
    int v = blockIdx.x * 4 + wid;
    if (v >= N) return;
    int rs = row_start[v], re = row_start[v + 1];
    float ax = 0.f, ay = 0.f, az = 0.f, aw = 0.f;
    for (int e = rs + lane; e < re; e += 64) {
        float4 f = hs0[csr_src[e]];
        ax += f.x; ay += f.y; az += f.z; aw += f.w;
    }
#pragma unroll
    for (int off = 32; off; off >>= 1) {
        ax += __shfl_xor(ax, off);
        ay += __shfl_xor(ay, off);
        az += __shfl_xor(az, off);
        aw += __shfl_xor(aw, off);
    }
    float nd = norm_dst[v];
    float r = sb[lane] + nd * (ax * sW[lane] + ay * sW[64 + lane] +
                               az * sW[128 + lane] + aw * sW[192 + lane]);
    r = fmaxf(r, 0.0f) * norm_src[v];
    out[(size_t)v * 64 + lane] = f_to_fp8(r);
}

// ---------------------------------------------------------------------------
// Layers 2-4: H=64 -> H=64. One wave = 8 nodes (proven sweet spot).
// fp8 gathers (3.2 MB table, L2-resident per XCD); f32 accumulate; f16 MFMA.
// Layers 2-3 write fp8 (scaled by norm_src); layer 4 writes f16 for pooling.
// ---------------------------------------------------------------------------
#define LOADIDX(IDX, E0)                                                \
    _Pragma("unroll")                                                   \
    for (int j = 0; j < 16; ++j) IDX[j] = csr_src[(E0) + j];

#define GATHER(T, IDX)                                                  \
    _Pragma("unroll")                                                   \
    for (int j = 0; j < 16; ++j) {                                      \
        unsigned uu = (unsigned)IDX[j];                                 \
        if (uu >= (unsigned)N_NODES) uu = 0;                            \
        T[j] = hs_in[(size_t)uu * 64 + lane];                           \
    }

#define ACCUM(T)                                                        \
    _Pragma("unroll")                                                   \
    for (int j = 0; j < 16; ++j) {                                      \
        while (ecur == bound) {                                         \
            sAgg[wavei][cur - vbase][lane] =                            \
                (_Float16)(acc * norm_dst[cur]);                        \
            acc = 0.0f;                                                 \
            ++cur;                                                      \
            bound = (cur < vend) ? row_start[cur + 1] : 0x7fffffff;     \
        }                                                               \
        acc += fp8_to_f(T[j]);                                          \
        ++ecur;                                                         \
    }

__global__ __launch_bounds__(256) void conv64_kernel(
        const unsigned char* __restrict__ hs_in,
        const int* __restrict__ row_start,
        const int* __restrict__ csr_src,
        const float* __restrict__ norm_src,
        const float* __restrict__ norm_dst,
        const _Float16* __restrict__ WT, const float* __restrict__ b,
        unsigned char* __restrict__ out8, _Float16* __restrict__ outh,
        int out_half, int N) {
    __shared__ _Float16 sAgg[4][16][72];
    const int lane = threadIdx.x & 63;
    const int wavei = __builtin_amdgcn_readfirstlane(threadIdx.x >> 6);
    const int vbase = blockIdx.x * 32 + wavei * 8;
    if (vbase >= N) return;                       // no barriers => safe

    const int vend = min(vbase + 8, N);
    const int rs = row_start[vbase];
    const int re = row_start[vend];
    int cur = vbase;
    int bound = row_start[vbase + 1];
    int ecur = rs;
    float acc = 0.0f;
    int nbp = (re - rs + 15) >> 4;
    int e = rs;
    int idxA[16], idxB[16];
    unsigned char tA[16], tB[16];

    if (nbp > 0) {
        LOADIDX(idxA, e);
        GATHER(tA, idxA);
        LOADIDX(idxB, e + 16);
        int k = 0;
        while (k + 2 <= nbp) {
            GATHER(tB, idxB);
            LOADIDX(idxA, e + 32);
            ACCUM(tA);
            if (k + 2 < nbp) {
                GATHER(tA, idxA);
                LOADIDX(idxB, e + 48);
            }
            ACCUM(tB);
            k += 2; e += 32;
        }
        if (k < nbp) { ACCUM(tA); }
    }
    while (cur < vend) {
        sAgg[wavei][cur - vbase][lane] = (_Float16)(acc * norm_dst[cur]);
        acc = 0.0f;
        ++cur;
    }

    const int l15 = lane & 15;
    const int quad = lane >> 4;
    const _Float16* aRow = &sAgg[wavei][l15][quad * 8];
    half8 a0 = *(const half8*)(aRow);
    half8 a1 = *(const half8*)(aRow + 32);

    floatx4 c[4];
#pragma unroll
    for (int nt = 0; nt < 4; ++nt) c[nt] = (floatx4){0.f, 0.f, 0.f, 0.f};

#pragma unroll
    for (int nt = 0; nt < 4; ++nt) {
        const _Float16* bp = WT + ((size_t)(nt * 16 + l15)) * 64 + quad * 8;
        half8 b0 = *(const half8*)bp;
        half8 b1 = *(const half8*)(bp + 32);
        c[nt] = __builtin_amdgcn_mfma_f32_16x16x32_f16(a0, b0, c[nt], 0, 0, 0);
        c[nt] = __builtin_amdgcn_mfma_f32_16x16x32_f16(a1, b1, c[nt], 0, 0, 0);
    }

#pragma unroll
    for (int nt = 0; nt < 4; ++nt) {
        float bias = b[nt * 16 + l15];
#pragma unroll
        for (int r = 0; r < 4; ++r) {
            int m = quad * 4 + r;
            int v = vbase + m;
            if (m < 8 && v < N) {
                float val = fmaxf(c[nt][r] + bias, 0.0f);
                if (out_half) {
                    outh[(size_t)v * 64 + nt * 16 + l15] = (_Float16)val;
                } else {
                    val *= norm_src[v];
                    out8[(size_t)v * 64 + nt * 16 + l15] = f_to_fp8(val);
                }
            }
        }
    }
}

// ---------------------------------------------------------------------------
// Pool stage 1: each wave owns 32 contiguous nodes (f16 input); one f32
// atomicAdd per graph segment per lane into gacc[64][64].
// ---------------------------------------------------------------------------
__global__ __launch_bounds__(256) void pool1_kernel(const _Float16* __restrict__ h,
                                                    const int* __restrict__ graph_ids,
                                                    float* __restrict__ gacc, int N) {
    const int lane = threadIdx.x & 63;
    const int wavei = threadIdx.x >> 6;
    int base = blockIdx.x * 128 + wavei * 32;
    if (base >= N) return;
    int end = min(base + 32, N);
    float acc = 0.0f;
    int g_cur = graph_ids[base];
    int v = base;
    for (; v + 8 <= end; v += 8) {
        _Float16 t[8];
#pragma unroll
        for (int j = 0; j < 8; ++j) t[j] = h[(size_t)(v + j) * 64 + lane];
#pragma unroll
        for (int j = 0; j < 8; ++j) {
            int g = graph_ids[v + j];              // wave-uniform
            if (g != g_cur) { atomicAdd(&gacc[g_cur * 64 + lane], acc); acc = 0.0f; g_cur = g; }
            acc += (float)t[j];
        }
    }
    for (; v < end; ++v) {
        int g = graph_ids[v];
        if (g != g_cur) { atomicAdd(&gacc[g_cur * 64 + lane], acc); acc = 0.0f; g_cur = g; }
        acc += (float)h[(size_t)v * 64 + lane];
    }
    atomicAdd(&gacc[g_cur * 64 + lane], acc);
}

// ---------------------------------------------------------------------------
// Pool stage 2: one wave per graph (16 blocks x 4 waves).
// ---------------------------------------------------------------------------
__global__ void pool2_kernel(const float* __restrict__ gacc, const float* __restrict__ gcnt,
                             const float* __restrict__ Wout, const float* __restrict__ bout,
                             float* __restrict__ out) {
    int lane = threadIdx.x & 63;
    int g = blockIdx.x * 4 + (threadIdx.x >> 6);   // 64 waves total
    float p = (gacc[g * 64 + lane] / gcnt[g]) * Wout[lane];
#pragma unroll
    for (int off = 32; off; off >>= 1) p += __shfl_xor(p, off);
    if (lane == 0) out[g] = 1.0f / (1.0f + expf(-(p + bout[0])));
}

// ---------------------------------------------------------------------------
extern "C" void kernel_launch(void* const* d_in, const int* in_sizes, int n_in,
                              void* d_out, int out_size, void* d_ws, size_t ws_size,
                              hipStream_t stream) {
    const int* src = (const int*)d_in[0];
    const int* dst = (const int*)d_in[1];
    const int* graph_ids = (const int*)d_in[2];
    const float* W1 = (const float*)d_in[3];
    const float* b1 = (const float*)d_in[4];
    const float* W2 = (const float*)d_in[5];
    const float* b2 = (const float*)d_in[6];
    const float* W3 = (const float*)d_in[7];
    const float* b3 = (const float*)d_in[8];
    const float* W4 = (const float*)d_in[9];
    const float* b4 = (const float*)d_in[10];
    const float* Wout = (const float*)d_in[11];
    const float* bout = (const float*)d_in[12];
    float* out = (float*)d_out;

    const int N = N_NODES, E = N_EDGES;

    _Float16* bufH = (_Float16*)d_ws;                      // N*64 f16 (layer-4 out)
    unsigned char* buf8A = (unsigned char*)(bufH + (size_t)N * 64);  // N*64 fp8
    unsigned char* buf8B = buf8A + (size_t)N * 64;                   // N*64 fp8
    _Float16* WT   = (_Float16*)(buf8B + (size_t)N * 64);  // 3*4096 f16
    float* gacc = (float*)(WT + 3 * 4096);                 // 64*64 f32
    float* gcnt = gacc + 64 * 64;                          // 64 f32
    float* hs0 = gcnt + 64;                                // N*4 f32 (16B-aligned)
    float* norm_src = hs0 + (size_t)N * 4;                 // N
    float* norm_dst = norm_src + N;                        // N
    int* csr_src   = (int*)(norm_dst + N);                 // E
    int* row_start = csr_src + E;                          // N+1
    int* blk_sums  = row_start + (N + 1);                  // NB
    unsigned char* inpart  = (unsigned char*)(blk_sums + NB + 1);    // NS*N u8
    unsigned char* outpart = inpart + (size_t)NS * N;                // NS*N u8
    unsigned char* rank    = outpart + (size_t)NS * N;               // E u8

    // hist (512) + WT transpose (48) + gacc/gcnt zero (1)
    hist_wt_kernel<<<NP * NS + 49, 256, 0, stream>>>(src, dst, inpart, outpart, rank,
                                                     W2, W3, W4, WT, gacc);
    scan_block_feat_kernel<<<NB, 256, 0, stream>>>(inpart, outpart, graph_ids,
                                                   row_start, blk_sums,
                                                   norm_src, norm_dst, (float4*)hs0, gcnt, N);
    scan_add_prefix_kernel<<<NB, 256, 0, stream>>>(row_start, blk_sums, inpart, N);
    csr_fill_kernel<<<(E / 4 + 255) / 256, 256, 0, stream>>>(src, dst, row_start, inpart,
                                                             rank, csr_src);

    conv4_kernel<<<(N + 3) / 4, 256, 0, stream>>>((const float4*)hs0, row_start, csr_src,
                                                  norm_src, norm_dst, W1, b1, buf8A, N);
    const int CB = (N + 31) / 32;   // 256 threads = 4 waves x 8 nodes
    conv64_kernel<<<CB, 256, 0, stream>>>(buf8A, row_start, csr_src, norm_src, norm_dst,
                                          WT + 0 * 4096, b2, buf8B, (_Float16*)nullptr, 0, N);
    conv64_kernel<<<CB, 256, 0, stream>>>(buf8B, row_start, csr_src, norm_src, norm_dst,
                                          WT + 1 * 4096, b3, buf8A, (_Float16*)nullptr, 0, N);
    conv64_kernel<<<CB, 256, 0, stream>>>(buf8A, row_start, csr_src, norm_src, norm_dst,
                                          WT + 2 * 4096, b4, (unsigned char*)nullptr, bufH, 1, N);

    pool1_kernel<<<(N + 127) / 128, 256, 0, stream>>>(bufH, graph_ids, gacc, N);
    pool2_kernel<<<16, 256, 0, stream>>>(gacc, gcnt, Wout, bout, out);
}

// Round 14
// 221.331 us; speedup vs baseline: 1.0863x; 1.0863x over previous
//
#include <hip/hip_runtime.h>
#include <hip/hip_fp8.h>
#include <math.h>

#define N_NODES 50000
#define N_EDGES 800000
#define NP 8                      // node partitions (6250 nodes each)
#define NS 64                     // edge segments (12500 edges each)
#define PSZ (N_NODES / NP)        // 6250
#define SSZ (N_EDGES / NS)        // 12500
#define NB 196                    // ceil(N/256)

typedef _Float16 half8 __attribute__((ext_vector_type(8)));
typedef float floatx4 __attribute__((ext_vector_type(4)));

// ---------------- fp8 e4m3 (OCP) helpers — HW cvt on gfx950 ----------------
__device__ __forceinline__ unsigned char f_to_fp8(float f) {
    __hip_fp8_e4m3 q(f);
    return (unsigned char)q.__x;
}
__device__ __forceinline__ float fp8_to_f(unsigned char u) {
    __hip_fp8_e4m3 q;
    q.__x = (__hip_fp8_storage_t)u;
    return (float)q;
}

// ---------------------------------------------------------------------------
// Fused: partitioned LDS histogram (blocks 0..NP*NS-1) + WT transpose +
// gacc/gcnt zeroing. Packed u32 counters (in low16 / out high16); the
// atomicAdd return's low bits are the edge's within-segment rank (u8).
// NS=64 => 512 hist blocks => 2 blocks/CU.
// ---------------------------------------------------------------------------
__global__ __launch_bounds__(256) void hist_wt_kernel(const int* __restrict__ src,
                                                      const int* __restrict__ dst,
                                                      unsigned char* __restrict__ inpart,
                                                      unsigned char* __restrict__ outpart,
                                                      unsigned char* __restrict__ rank,
                                                      const float* __restrict__ W2,
                                                      const float* __restrict__ W3,
                                                      const float* __restrict__ W4,
                                                      _Float16* __restrict__ WT,
                                                      float* __restrict__ gacc) {
    __shared__ int h[PSZ + 2];                   // pad to int4 multiple (6252)
    if (blockIdx.x >= NP * NS) {
        int wb = blockIdx.x - NP * NS;
        if (wb < 48) {                           // WT transpose: f32 [k][n] -> f16 [n][k]
            int i = wb * 256 + threadIdx.x;
            if (i < 3 * 4096) {
                int l = i >> 12;
                int r = i & 4095;
                int k = r >> 6, n = r & 63;
                const float* W = (l == 0) ? W2 : (l == 1) ? W3 : W4;
                WT[l * 4096 + n * 64 + k] = (_Float16)W[r];
            }
        } else {                                 // zero gacc[4096] + gcnt[64]
            for (int i = threadIdx.x; i < 64 * 64 + 64; i += 256) gacc[i] = 0.0f;
        }
        return;
    }
    int p = blockIdx.x / NS, s = blockIdx.x % NS;
    for (int i = threadIdx.x; i < (PSZ + 2) / 4 + 1; i += 256)
        if (4 * i < PSZ + 2) ((int4*)h)[i] = make_int4(0, 0, 0, 0);
    __syncthreads();
    int lo = p * PSZ;
    int ebase = s * SSZ;
    const int4* d4 = (const int4*)(dst + ebase);
    const int4* s4 = (const int4*)(src + ebase);
    unsigned char* rk = rank + ebase;
    for (int i = threadIdx.x; i < SSZ / 4; i += 256) {
        int4 d = d4[i];
        int4 sv = s4[i];
        int t;
        t = d.x - lo;  if ((unsigned)t < PSZ) rk[4 * i + 0] = (unsigned char)(atomicAdd(&h[t], 1) & 0xffff);
        t = d.y - lo;  if ((unsigned)t < PSZ) rk[4 * i + 1] = (unsigned char)(atomicAdd(&h[t], 1) & 0xffff);
        t = d.z - lo;  if ((unsigned)t < PSZ) rk[4 * i + 2] = (unsigned char)(atomicAdd(&h[t], 1) & 0xffff);
        t = d.w - lo;  if ((unsigned)t < PSZ) rk[4 * i + 3] = (unsigned char)(atomicAdd(&h[t], 1) & 0xffff);
        t = sv.x - lo; if ((unsigned)t < PSZ) atomicAdd(&h[t], 0x10000);
        t = sv.y - lo; if ((unsigned)t < PSZ) atomicAdd(&h[t], 0x10000);
        t = sv.z - lo; if ((unsigned)t < PSZ) atomicAdd(&h[t], 0x10000);
        t = sv.w - lo; if ((unsigned)t < PSZ) atomicAdd(&h[t], 0x10000);
    }
    __syncthreads();
    unsigned char* ip = inpart + (size_t)s * N_NODES + lo;
    unsigned char* op = outpart + (size_t)s * N_NODES + lo;
    for (int i = threadIdx.x; i < PSZ / 2; i += 256) {
        int v0 = h[2 * i], v1 = h[2 * i + 1];
        uchar2 iv, ov;
        iv.x = (unsigned char)(v0 & 0xff);
        iv.y = (unsigned char)(v1 & 0xff);
        ov.x = (unsigned char)((v0 >> 16) & 0xff);
        ov.y = (unsigned char)((v1 >> 16) & 0xff);
        ((uchar2*)ip)[i] = iv;
        ((uchar2*)op)[i] = ov;
    }
}

// ---------------------------------------------------------------------------
// Fused: reduce u8 segment partials -> degrees AND rewrite inpart in place
// into the exclusive within-row segment prefix (same pass — thread owns node
// i); features/norms (fp8 table); block scan; per-graph node counts.
// ---------------------------------------------------------------------------
__global__ void scan_block_feat_kernel(unsigned char* __restrict__ inpart,
                                       const unsigned char* __restrict__ outpart,
                                       const int* __restrict__ graph_ids,
                                       int* __restrict__ row_start, int* __restrict__ blk_sums,
                                       float* __restrict__ norm_src, float* __restrict__ norm_dst,
                                       uchar4* __restrict__ hs0, float* __restrict__ gcnt, int N) {
    __shared__ int ghist[64];
    if (threadIdx.x < 64) ghist[threadIdx.x] = 0;
    int i = blockIdx.x * 256 + threadIdx.x;
    int din_i = 0, dout_i = 0;
    if (i < N) {
        unsigned char run = 0;
#pragma unroll
        for (int s = 0; s < NS; ++s) {
            unsigned char c = inpart[(size_t)s * N_NODES + i];
            inpart[(size_t)s * N_NODES + i] = run;     // prefix rewrite in place
            run = (unsigned char)(run + c);
            dout_i += outpart[(size_t)s * N_NODES + i];
        }
        din_i = (int)run;
        float din = (float)din_i;
        float dout = (float)dout_i;
        float ns = 1.0f / sqrtf(fmaxf(dout, 1.0f));
        float nd = 1.0f / sqrtf(fmaxf(din, 1.0f));
        norm_src[i] = ns;
        norm_dst[i] = nd;
        float h1 = din;
        float h2 = (din - 3.0f > 0.0f) ? 1.0f : 0.0f;
        float h3 = 3.0f / din;
        float h4 = (din - 4.0f > 0.0f) ? 1.0f : 0.0f;
        uchar4 q;
        q.x = f_to_fp8(h1 * ns);
        q.y = f_to_fp8(h2 * ns);
        q.z = f_to_fp8(h3 * ns);
        q.w = f_to_fp8(h4 * ns);
        hs0[i] = q;
    }
    __syncthreads();
    if (i < N) atomicAdd(&ghist[graph_ids[i]], 1);
    int lane = threadIdx.x & 63;
    int wid = threadIdx.x >> 6;
    int x = din_i;
#pragma unroll
    for (int off = 1; off < 64; off <<= 1) {
        int t = __shfl_up(x, off);
        if (lane >= off) x += t;
    }
    __shared__ int wsum[4];
    if (lane == 63) wsum[wid] = x;
    __syncthreads();
    int woff = 0;
    for (int w = 0; w < wid; ++w) woff += wsum[w];
    int incl = x + woff;
    if (i < N) row_start[i] = incl - din_i;
    if (threadIdx.x == 255) blk_sums[blockIdx.x] = incl;
    if (threadIdx.x < 64 && ghist[threadIdx.x] > 0)
        atomicAdd(&gcnt[threadIdx.x], (float)ghist[threadIdx.x]);
}

// ---------------------------------------------------------------------------
// Slim: finalize row_start only (each block re-scans the 196 block sums
// locally — the heavy inpart rewrite moved into scan_block_feat).
// ---------------------------------------------------------------------------
__global__ void row_add_kernel(int* __restrict__ row_start,
                               const int* __restrict__ blk_sums, int N) {
    __shared__ int sOff[256];
    int t = threadIdx.x;
    int v = (t < NB) ? blk_sums[t] : 0;
    int lane = t & 63;
    int wid = t >> 6;
    int x = v;
#pragma unroll
    for (int off = 1; off < 64; off <<= 1) {
        int tt = __shfl_up(x, off);
        if (lane >= off) x += tt;
    }
    __shared__ int wsum[4];
    if (lane == 63) wsum[wid] = x;
    __syncthreads();
    int woff = 0;
    for (int w = 0; w < wid; ++w) woff += wsum[w];
    sOff[t] = x + woff - v;              // exclusive prefix of blk_sums
    __syncthreads();
    int i = blockIdx.x * 256 + threadIdx.x;
    if (blockIdx.x == 0 && threadIdx.x == 0) row_start[N] = N_EDGES;
    if (i < N) row_start[i] += sOff[blockIdx.x];
}

// ---------------------------------------------------------------------------
// Rank-based CSR fill: pos = row_start[d] + pref[s][d] + rank[e].
// No atomics, no LDS, grid-stride, fully parallel.
// ---------------------------------------------------------------------------
__global__ __launch_bounds__(256) void csr_fill_kernel(const int* __restrict__ src,
                                                       const int* __restrict__ dst,
                                                       const int* __restrict__ row_start,
                                                       const unsigned char* __restrict__ inpart,
                                                       const unsigned char* __restrict__ rank,
                                                       int* __restrict__ csr_src) {
    int i = blockIdx.x * 256 + threadIdx.x;          // edge-quad index
    if (i >= N_EDGES / 4) return;
    int4 d = ((const int4*)dst)[i];
    int4 sv = ((const int4*)src)[i];
    uchar4 rk = ((const uchar4*)rank)[i];
    int s = (4 * i) / SSZ;                           // uniform per SSZ/4 quads
    const unsigned char* pref = inpart + (size_t)s * N_NODES;
    csr_src[row_start[d.x] + (int)pref[d.x] + (int)rk.x] = sv.x;
    csr_src[row_start[d.y] + (int)pref[d.y] + (int)rk.y] = sv.y;
    csr_src[row_start[d.z] + (int)pref[d.z] + (int)rk.z] = sv.z;
    csr_src[row_start[d.w] + (int)pref[d.w] + (int)rk.w] = sv.w;
}

// ---------------------------------------------------------------------------
// Layer 1: IN=4 -> H=64. One wave per node; lanes split neighbors.
// Gather table is fp8x4 (uchar4, 200 KB — L2-hot; 4 B/lane scattered).
// Output fp8, pre-scaled by norm_src.
// ---------------------------------------------------------------------------
__global__ void conv4_kernel(const uchar4* __restrict__ hs0,
                             const int* __restrict__ row_start,
                             const int* __restrict__ csr_src,
                             const float* __restrict__ norm_src,
                             const float* __restrict__ norm_dst,
                             const float* __restrict__ W, const float* __restrict__ b,
                             unsigned char* __restrict__ out, int N) {
    __shared__ float sW[4 * 64];
    __shared__ float sb[64];
    sW[threadIdx.x] = W[threadIdx.x];
    if (threadIdx.x < 64) sb[threadIdx.x] = b[threadIdx.x];
    __syncthreads();
    int lane = threadIdx.x & 63;
    int wid = threadIdx.x >> 6;
    int v = blockIdx.x * 4 + wid;
    if (v >= N) return;
    int rs = row_start[v], re = row_start[v + 1];
    float ax = 0.f, ay = 0.f, az = 0.f, aw = 0.f;
    for (int e = rs + lane; e < re; e += 64) {
        uchar4 f = hs0[csr_src[e]];
        ax += fp8_to_f(f.x); ay += fp8_to_f(f.y);
        az += fp8_to_f(f.z); aw += fp8_to_f(f.w);
    }
#pragma unroll
    for (int off = 32; off; off >>= 1) {
        ax += __shfl_xor(ax, off);
        ay += __shfl_xor(ay, off);
        az += __shfl_xor(az, off);
        aw += __shfl_xor(aw, off);
    }
    float nd = norm_dst[v];
    float r = sb[lane] + nd * (ax * sW[lane] + ay * sW[64 + lane] +
                               az * sW[128 + lane] + aw * sW[192 + lane]);
    r = fmaxf(r, 0.0f) * norm_src[v];
    out[(size_t)v * 64 + lane] = f_to_fp8(r);
}

// ---------------------------------------------------------------------------
// Layers 2-4: H=64 -> H=64. One wave = 8 nodes (proven sweet spot).
// fp8 gathers (3.2 MB table, L2-resident per XCD); f32 accumulate; f16 MFMA.
// Layers 2-3 write fp8 (scaled by norm_src); layer 4 writes f16 for pooling.
// ---------------------------------------------------------------------------
#define LOADIDX(IDX, E0)                                                \
    _Pragma("unroll")                                                   \
    for (int j = 0; j < 16; ++j) IDX[j] = csr_src[(E0) + j];

#define GATHER(T, IDX)                                                  \
    _Pragma("unroll")                                                   \
    for (int j = 0; j < 16; ++j) {                                      \
        unsigned uu = (unsigned)IDX[j];                                 \
        if (uu >= (unsigned)N_NODES) uu = 0;                            \
        T[j] = hs_in[(size_t)uu * 64 + lane];                           \
    }

#define ACCUM(T)                                                        \
    _Pragma("unroll")                                                   \
    for (int j = 0; j < 16; ++j) {                                      \
        while (ecur == bound) {                                         \
            sAgg[wavei][cur - vbase][lane] =                            \
                (_Float16)(acc * norm_dst[cur]);                        \
            acc = 0.0f;                                                 \
            ++cur;                                                      \
            bound = (cur < vend) ? row_start[cur + 1] : 0x7fffffff;     \
        }                                                               \
        acc += fp8_to_f(T[j]);                                          \
        ++ecur;                                                         \
    }

__global__ __launch_bounds__(256) void conv64_kernel(
        const unsigned char* __restrict__ hs_in,
        const int* __restrict__ row_start,
        const int* __restrict__ csr_src,
        const float* __restrict__ norm_src,
        const float* __restrict__ norm_dst,
        const _Float16* __restrict__ WT, const float* __restrict__ b,
        unsigned char* __restrict__ out8, _Float16* __restrict__ outh,
        int out_half, int N) {
    __shared__ _Float16 sAgg[4][16][72];
    const int lane = threadIdx.x & 63;
    const int wavei = __builtin_amdgcn_readfirstlane(threadIdx.x >> 6);
    const int vbase = blockIdx.x * 32 + wavei * 8;
    if (vbase >= N) return;                       // no barriers => safe

    const int vend = min(vbase + 8, N);
    const int rs = row_start[vbase];
    const int re = row_start[vend];
    int cur = vbase;
    int bound = row_start[vbase + 1];
    int ecur = rs;
    float acc = 0.0f;
    int nbp = (re - rs + 15) >> 4;
    int e = rs;
    int idxA[16], idxB[16];
    unsigned char tA[16], tB[16];

    if (nbp > 0) {
        LOADIDX(idxA, e);
        GATHER(tA, idxA);
        LOADIDX(idxB, e + 16);
        int k = 0;
        while (k + 2 <= nbp) {
            GATHER(tB, idxB);
            LOADIDX(idxA, e + 32);
            ACCUM(tA);
            if (k + 2 < nbp) {
                GATHER(tA, idxA);
                LOADIDX(idxB, e + 48);
            }
            ACCUM(tB);
            k += 2; e += 32;
        }
        if (k < nbp) { ACCUM(tA); }
    }
    while (cur < vend) {
        sAgg[wavei][cur - vbase][lane] = (_Float16)(acc * norm_dst[cur]);
        acc = 0.0f;
        ++cur;
    }

    const int l15 = lane & 15;
    const int quad = lane >> 4;
    const _Float16* aRow = &sAgg[wavei][l15][quad * 8];
    half8 a0 = *(const half8*)(aRow);
    half8 a1 = *(const half8*)(aRow + 32);

    floatx4 c[4];
#pragma unroll
    for (int nt = 0; nt < 4; ++nt) c[nt] = (floatx4){0.f, 0.f, 0.f, 0.f};

#pragma unroll
    for (int nt = 0; nt < 4; ++nt) {
        const _Float16* bp = WT + ((size_t)(nt * 16 + l15)) * 64 + quad * 8;
        half8 b0 = *(const half8*)bp;
        half8 b1 = *(const half8*)(bp + 32);
        c[nt] = __builtin_amdgcn_mfma_f32_16x16x32_f16(a0, b0, c[nt], 0, 0, 0);
        c[nt] = __builtin_amdgcn_mfma_f32_16x16x32_f16(a1, b1, c[nt], 0, 0, 0);
    }

#pragma unroll
    for (int nt = 0; nt < 4; ++nt) {
        float bias = b[nt * 16 + l15];
#pragma unroll
        for (int r = 0; r < 4; ++r) {
            int m = quad * 4 + r;
            int v = vbase + m;
            if (m < 8 && v < N) {
                float val = fmaxf(c[nt][r] + bias, 0.0f);
                if (out_half) {
                    outh[(size_t)v * 64 + nt * 16 + l15] = (_Float16)val;
                } else {
                    val *= norm_src[v];
                    out8[(size_t)v * 64 + nt * 16 + l15] = f_to_fp8(val);
                }
            }
        }
    }
}

// ---------------------------------------------------------------------------
// Pool stage 1: each wave owns 32 contiguous nodes (f16 input); one f32
// atomicAdd per graph segment per lane into gacc[64][64].
// ---------------------------------------------------------------------------
__global__ __launch_bounds__(256) void pool1_kernel(const _Float16* __restrict__ h,
                                                    const int* __restrict__ graph_ids,
                                                    float* __restrict__ gacc, int N) {
    const int lane = threadIdx.x & 63;
    const int wavei = threadIdx.x >> 6;
    int base = blockIdx.x * 128 + wavei * 32;
    if (base >= N) return;
    int end = min(base + 32, N);
    float acc = 0.0f;
    int g_cur = graph_ids[base];
    int v = base;
    for (; v + 8 <= end; v += 8) {
        _Float16 t[8];
#pragma unroll
        for (int j = 0; j < 8; ++j) t[j] = h[(size_t)(v + j) * 64 + lane];
#pragma unroll
        for (int j = 0; j < 8; ++j) {
            int g = graph_ids[v + j];              // wave-uniform
            if (g != g_cur) { atomicAdd(&gacc[g_cur * 64 + lane], acc); acc = 0.0f; g_cur = g; }
            acc += (float)t[j];
        }
    }
    for (; v < end; ++v) {
        int g = graph_ids[v];
        if (g != g_cur) { atomicAdd(&gacc[g_cur * 64 + lane], acc); acc = 0.0f; g_cur = g; }
        acc += (float)h[(size_t)v * 64 + lane];
    }
    atomicAdd(&gacc[g_cur * 64 + lane], acc);
}

// ---------------------------------------------------------------------------
// Pool stage 2: one wave per graph (16 blocks x 4 waves).
// ---------------------------------------------------------------------------
__global__ void pool2_kernel(const float* __restrict__ gacc, const float* __restrict__ gcnt,
                             const float* __restrict__ Wout, const float* __restrict__ bout,
                             float* __restrict__ out) {
    int lane = threadIdx.x & 63;
    int g = blockIdx.x * 4 + (threadIdx.x >> 6);   // 64 waves total
    float p = (gacc[g * 64 + lane] / gcnt[g]) * Wout[lane];
#pragma unroll
    for (int off = 32; off; off >>= 1) p += __shfl_xor(p, off);
    if (lane == 0) out[g] = 1.0f / (1.0f + expf(-(p + bout[0])));
}

// ---------------------------------------------------------------------------
extern "C" void kernel_launch(void* const* d_in, const int* in_sizes, int n_in,
                              void* d_out, int out_size, void* d_ws, size_t ws_size,
                              hipStream_t stream) {
    const int* src = (const int*)d_in[0];
    const int* dst = (const int*)d_in[1];
    const int* graph_ids = (const int*)d_in[2];
    const float* W1 = (const float*)d_in[3];
    const float* b1 = (const float*)d_in[4];
    const float* W2 = (const float*)d_in[5];
    const float* b2 = (const float*)d_in[6];
    const float* W3 = (const float*)d_in[7];
    const float* b3 = (const float*)d_in[8];
    const float* W4 = (const float*)d_in[9];
    const float* b4 = (const float*)d_in[10];
    const float* Wout = (const float*)d_in[11];
    const float* bout = (const float*)d_in[12];
    float* out = (float*)d_out;

    const int N = N_NODES, E = N_EDGES;

    _Float16* bufH = (_Float16*)d_ws;                      // N*64 f16 (layer-4 out)
    unsigned char* buf8A = (unsigned char*)(bufH + (size_t)N * 64);  // N*64 fp8
    unsigned char* buf8B = buf8A + (size_t)N * 64;                   // N*64 fp8
    _Float16* WT   = (_Float16*)(buf8B + (size_t)N * 64);  // 3*4096 f16
    float* gacc = (float*)(WT + 3 * 4096);                 // 64*64 f32
    float* gcnt = gacc + 64 * 64;                          // 64 f32
    unsigned char* hs0 = (unsigned char*)(gcnt + 64);      // N*4 fp8 (4B-aligned)
    float* norm_src = (float*)(hs0 + (size_t)N * 4);       // N
    float* norm_dst = norm_src + N;                        // N
    int* csr_src   = (int*)(norm_dst + N);                 // E
    int* row_start = csr_src + E;                          // N+1
    int* blk_sums  = row_start + (N + 1);                  // NB
    unsigned char* inpart  = (unsigned char*)(blk_sums + NB + 1);    // NS*N u8
    unsigned char* outpart = inpart + (size_t)NS * N;                // NS*N u8
    unsigned char* rank    = outpart + (size_t)NS * N;               // E u8

    // hist (512) + WT transpose (48) + gacc/gcnt zero (1)
    hist_wt_kernel<<<NP * NS + 49, 256, 0, stream>>>(src, dst, inpart, outpart, rank,
                                                     W2, W3, W4, WT, gacc);
    scan_block_feat_kernel<<<NB, 256, 0, stream>>>(inpart, outpart, graph_ids,
                                                   row_start, blk_sums,
                                                   norm_src, norm_dst, (uchar4*)hs0, gcnt, N);
    row_add_kernel<<<NB, 256, 0, stream>>>(row_start, blk_sums, N);
    csr_fill_kernel<<<(E / 4 + 255) / 256, 256, 0, stream>>>(src, dst, row_start, inpart,
                                                             rank, csr_src);

    conv4_kernel<<<(N + 3) / 4, 256, 0, stream>>>((const uchar4*)hs0, row_start, csr_src,
                                                  norm_src, norm_dst, W1, b1, buf8A, N);
    const int CB = (N + 31) / 32;   // 256 threads = 4 waves x 8 nodes
    conv64_kernel<<<CB, 256, 0, stream>>>(buf8A, row_start, csr_src, norm_src, norm_dst,
                                          WT + 0 * 4096, b2, buf8B, (_Float16*)nullptr, 0, N);
    conv64_kernel<<<CB, 256, 0, stream>>>(buf8B, row_start, csr_src, norm_src, norm_dst,
                                          WT + 1 * 4096, b3, buf8A, (_Float16*)nullptr, 0, N);
    conv64_kernel<<<CB, 256, 0, stream>>>(buf8A, row_start, csr_src, norm_src, norm_dst,
                                          WT + 2 * 4096, b4, (unsigned char*)nullptr, bufH, 1, N);

    pool1_kernel<<<(N + 127) / 128, 256, 0, stream>>>(bufH, graph_ids, gacc, N);
    pool2_kernel<<<16, 256, 0, stream>>>(gacc, gcnt, Wout, bout, out);
}

// Round 15
// 210.826 us; speedup vs baseline: 1.1405x; 1.0498x over previous
//
#include <hip/hip_runtime.h>
#include <hip/hip_fp8.h>
#include <math.h>

#define N_NODES 50000
#define N_EDGES 800000
#define NP 8                      // node partitions (6250 nodes each)
#define NS 64                     // edge segments (12500 edges each)
#define PSZ (N_NODES / NP)        // 6250
#define SSZ (N_EDGES / NS)        // 12500
#define NB 196                    // ceil(N/256)

typedef _Float16 half8 __attribute__((ext_vector_type(8)));
typedef float floatx4 __attribute__((ext_vector_type(4)));

// ---------------- fp8 e4m3 (OCP) helpers — HW cvt on gfx950 ----------------
__device__ __forceinline__ unsigned char f_to_fp8(float f) {
    __hip_fp8_e4m3 q(f);
    return (unsigned char)q.__x;
}
__device__ __forceinline__ float fp8_to_f(unsigned char u) {
    __hip_fp8_e4m3 q;
    q.__x = (__hip_fp8_storage_t)u;
    return (float)q;
}

// ---------------------------------------------------------------------------
// Fused: partitioned LDS histogram (blocks 0..NP*NS-1) + WT transpose +
// gacc/gcnt zeroing. Packed u32 counters (in low16 / out high16); the
// atomicAdd return's low bits are the edge's within-segment rank (u8).
// NS=64 => 512 hist blocks => 2 blocks/CU.
// ---------------------------------------------------------------------------
__global__ __launch_bounds__(256) void hist_wt_kernel(const int* __restrict__ src,
                                                      const int* __restrict__ dst,
                                                      unsigned char* __restrict__ inpart,
                                                      unsigned char* __restrict__ outpart,
                                                      unsigned char* __restrict__ rank,
                                                      const float* __restrict__ W2,
                                                      const float* __restrict__ W3,
                                                      const float* __restrict__ W4,
                                                      _Float16* __restrict__ WT,
                                                      float* __restrict__ gacc) {
    __shared__ int h[PSZ + 2];                   // pad to int4 multiple (6252)
    if (blockIdx.x >= NP * NS) {
        int wb = blockIdx.x - NP * NS;
        if (wb < 48) {                           // WT transpose: f32 [k][n] -> f16 [n][k]
            int i = wb * 256 + threadIdx.x;
            if (i < 3 * 4096) {
                int l = i >> 12;
                int r = i & 4095;
                int k = r >> 6, n = r & 63;
                const float* W = (l == 0) ? W2 : (l == 1) ? W3 : W4;
                WT[l * 4096 + n * 64 + k] = (_Float16)W[r];
            }
        } else {                                 // zero gacc[4096] + gcnt[64]
            for (int i = threadIdx.x; i < 64 * 64 + 64; i += 256) gacc[i] = 0.0f;
        }
        return;
    }
    int p = blockIdx.x / NS, s = blockIdx.x % NS;
    for (int i = threadIdx.x; i < (PSZ + 2) / 4 + 1; i += 256)
        if (4 * i < PSZ + 2) ((int4*)h)[i] = make_int4(0, 0, 0, 0);
    __syncthreads();
    int lo = p * PSZ;
    int ebase = s * SSZ;
    const int4* d4 = (const int4*)(dst + ebase);
    const int4* s4 = (const int4*)(src + ebase);
    unsigned char* rk = rank + ebase;
    for (int i = threadIdx.x; i < SSZ / 4; i += 256) {
        int4 d = d4[i];
        int4 sv = s4[i];
        int t;
        t = d.x - lo;  if ((unsigned)t < PSZ) rk[4 * i + 0] = (unsigned char)(atomicAdd(&h[t], 1) & 0xffff);
        t = d.y - lo;  if ((unsigned)t < PSZ) rk[4 * i + 1] = (unsigned char)(atomicAdd(&h[t], 1) & 0xffff);
        t = d.z - lo;  if ((unsigned)t < PSZ) rk[4 * i + 2] = (unsigned char)(atomicAdd(&h[t], 1) & 0xffff);
        t = d.w - lo;  if ((unsigned)t < PSZ) rk[4 * i + 3] = (unsigned char)(atomicAdd(&h[t], 1) & 0xffff);
        t = sv.x - lo; if ((unsigned)t < PSZ) atomicAdd(&h[t], 0x10000);
        t = sv.y - lo; if ((unsigned)t < PSZ) atomicAdd(&h[t], 0x10000);
        t = sv.z - lo; if ((unsigned)t < PSZ) atomicAdd(&h[t], 0x10000);
        t = sv.w - lo; if ((unsigned)t < PSZ) atomicAdd(&h[t], 0x10000);
    }
    __syncthreads();
    unsigned char* ip = inpart + (size_t)s * N_NODES + lo;
    unsigned char* op = outpart + (size_t)s * N_NODES + lo;
    for (int i = threadIdx.x; i < PSZ / 2; i += 256) {
        int v0 = h[2 * i], v1 = h[2 * i + 1];
        uchar2 iv, ov;
        iv.x = (unsigned char)(v0 & 0xff);
        iv.y = (unsigned char)(v1 & 0xff);
        ov.x = (unsigned char)((v0 >> 16) & 0xff);
        ov.y = (unsigned char)((v1 >> 16) & 0xff);
        ((uchar2*)ip)[i] = iv;
        ((uchar2*)op)[i] = ov;
    }
}

// ---------------------------------------------------------------------------
// Fused: reduce u8 segment partials -> degrees AND rewrite inpart in place
// into the exclusive within-row segment prefix; features/norms (fp8 table);
// block scan; per-graph node counts.
// ---------------------------------------------------------------------------
__global__ void scan_block_feat_kernel(unsigned char* __restrict__ inpart,
                                       const unsigned char* __restrict__ outpart,
                                       const int* __restrict__ graph_ids,
                                       int* __restrict__ row_start, int* __restrict__ blk_sums,
                                       float* __restrict__ norm_src, float* __restrict__ norm_dst,
                                       uchar4* __restrict__ hs0, float* __restrict__ gcnt, int N) {
    __shared__ int ghist[64];
    if (threadIdx.x < 64) ghist[threadIdx.x] = 0;
    int i = blockIdx.x * 256 + threadIdx.x;
    int din_i = 0, dout_i = 0;
    if (i < N) {
        unsigned char run = 0;
#pragma unroll
        for (int s = 0; s < NS; ++s) {
            unsigned char c = inpart[(size_t)s * N_NODES + i];
            inpart[(size_t)s * N_NODES + i] = run;     // prefix rewrite in place
            run = (unsigned char)(run + c);
            dout_i += outpart[(size_t)s * N_NODES + i];
        }
        din_i = (int)run;
        float din = (float)din_i;
        float dout = (float)dout_i;
        float ns = 1.0f / sqrtf(fmaxf(dout, 1.0f));
        float nd = 1.0f / sqrtf(fmaxf(din, 1.0f));
        norm_src[i] = ns;
        norm_dst[i] = nd;
        float h1 = din;
        float h2 = (din - 3.0f > 0.0f) ? 1.0f : 0.0f;
        float h3 = 3.0f / din;
        float h4 = (din - 4.0f > 0.0f) ? 1.0f : 0.0f;
        uchar4 q;
        q.x = f_to_fp8(h1 * ns);
        q.y = f_to_fp8(h2 * ns);
        q.z = f_to_fp8(h3 * ns);
        q.w = f_to_fp8(h4 * ns);
        hs0[i] = q;
    }
    __syncthreads();
    if (i < N) atomicAdd(&ghist[graph_ids[i]], 1);
    int lane = threadIdx.x & 63;
    int wid = threadIdx.x >> 6;
    int x = din_i;
#pragma unroll
    for (int off = 1; off < 64; off <<= 1) {
        int t = __shfl_up(x, off);
        if (lane >= off) x += t;
    }
    __shared__ int wsum[4];
    if (lane == 63) wsum[wid] = x;
    __syncthreads();
    int woff = 0;
    for (int w = 0; w < wid; ++w) woff += wsum[w];
    int incl = x + woff;
    if (i < N) row_start[i] = incl - din_i;
    if (threadIdx.x == 255) blk_sums[blockIdx.x] = incl;
    if (threadIdx.x < 64 && ghist[threadIdx.x] > 0)
        atomicAdd(&gcnt[threadIdx.x], (float)ghist[threadIdx.x]);
}

// ---------------------------------------------------------------------------
// Slim: finalize row_start only (each block re-scans the 196 block sums).
// ---------------------------------------------------------------------------
__global__ void row_add_kernel(int* __restrict__ row_start,
                               const int* __restrict__ blk_sums, int N) {
    __shared__ int sOff[256];
    int t = threadIdx.x;
    int v = (t < NB) ? blk_sums[t] : 0;
    int lane = t & 63;
    int wid = t >> 6;
    int x = v;
#pragma unroll
    for (int off = 1; off < 64; off <<= 1) {
        int tt = __shfl_up(x, off);
        if (lane >= off) x += tt;
    }
    __shared__ int wsum[4];
    if (lane == 63) wsum[wid] = x;
    __syncthreads();
    int woff = 0;
    for (int w = 0; w < wid; ++w) woff += wsum[w];
    sOff[t] = x + woff - v;              // exclusive prefix of blk_sums
    __syncthreads();
    int i = blockIdx.x * 256 + threadIdx.x;
    if (blockIdx.x == 0 && threadIdx.x == 0) row_start[N] = N_EDGES;
    if (i < N) row_start[i] += sOff[blockIdx.x];
}

// ---------------------------------------------------------------------------
// Rank-based CSR fill: pos = row_start[d] + pref[s][d] + rank[e].
// ---------------------------------------------------------------------------
__global__ __launch_bounds__(256) void csr_fill_kernel(const int* __restrict__ src,
                                                       const int* __restrict__ dst,
                                                       const int* __restrict__ row_start,
                                                       const unsigned char* __restrict__ inpart,
                                                       const unsigned char* __restrict__ rank,
                                                       int* __restrict__ csr_src) {
    int i = blockIdx.x * 256 + threadIdx.x;          // edge-quad index
    if (i >= N_EDGES / 4) return;
    int4 d = ((const int4*)dst)[i];
    int4 sv = ((const int4*)src)[i];
    uchar4 rk = ((const uchar4*)rank)[i];
    int s = (4 * i) / SSZ;                           // uniform per SSZ/4 quads
    const unsigned char* pref = inpart + (size_t)s * N_NODES;
    csr_src[row_start[d.x] + (int)pref[d.x] + (int)rk.x] = sv.x;
    csr_src[row_start[d.y] + (int)pref[d.y] + (int)rk.y] = sv.y;
    csr_src[row_start[d.z] + (int)pref[d.z] + (int)rk.z] = sv.z;
    csr_src[row_start[d.w] + (int)pref[d.w] + (int)rk.w] = sv.w;
}

// ---------------------------------------------------------------------------
// Layer 1: IN=4 -> H=64. fp8x4 gather table (200 KB, L2-hot).
// ---------------------------------------------------------------------------
__global__ void conv4_kernel(const uchar4* __restrict__ hs0,
                             const int* __restrict__ row_start,
                             const int* __restrict__ csr_src,
                             const float* __restrict__ norm_src,
                             const float* __restrict__ norm_dst,
                             const float* __restrict__ W, const float* __restrict__ b,
                             unsigned char* __restrict__ out, int N) {
    __shared__ float sW[4 * 64];
    __shared__ float sb[64];
    sW[threadIdx.x] = W[threadIdx.x];
    if (threadIdx.x < 64) sb[threadIdx.x] = b[threadIdx.x];
    __syncthreads();
    int lane = threadIdx.x & 63;
    int wid = threadIdx.x >> 6;
    int v = blockIdx.x * 4 + wid;
    if (v >= N) return;
    int rs = row_start[v], re = row_start[v + 1];
    float ax = 0.f, ay = 0.f, az = 0.f, aw = 0.f;
    for (int e = rs + lane; e < re; e += 64) {
        uchar4 f = hs0[csr_src[e]];
        ax += fp8_to_f(f.x); ay += fp8_to_f(f.y);
        az += fp8_to_f(f.z); aw += fp8_to_f(f.w);
    }
#pragma unroll
    for (int off = 32; off; off >>= 1) {
        ax += __shfl_xor(ax, off);
        ay += __shfl_xor(ay, off);
        az += __shfl_xor(az, off);
        aw += __shfl_xor(aw, off);
    }
    float nd = norm_dst[v];
    float r = sb[lane] + nd * (ax * sW[lane] + ay * sW[64 + lane] +
                               az * sW[128 + lane] + aw * sW[192 + lane]);
    r = fmaxf(r, 0.0f) * norm_src[v];
    out[(size_t)v * 64 + lane] = f_to_fp8(r);
}

// ---------------------------------------------------------------------------
// Layers 2-4: H=64 -> H=64. One wave = 8 nodes. fp8 gathers; f16 MFMA.
// Layers 2-3 write fp8 (scaled by norm_src). Layer 4 (do_pool) fuses mean-
// pool: N%8==0 => all 8 rows valid; sorted graph_ids => ~99% of waves span
// one graph. Fast path: per-lane row-sum + quad0/quad1 combine via
// shfl_xor(16) => 64 atomics/wave into L2-resident gacc. Boundary waves
// take per-node atomics. No bufH store, no pool1 pass.
// ---------------------------------------------------------------------------
#define LOADIDX(IDX, E0)                                                \
    _Pragma("unroll")                                                   \
    for (int j = 0; j < 16; ++j) IDX[j] = csr_src[(E0) + j];

#define GATHER(T, IDX)                                                  \
    _Pragma("unroll")                                                   \
    for (int j = 0; j < 16; ++j) {                                      \
        unsigned uu = (unsigned)IDX[j];                                 \
        if (uu >= (unsigned)N_NODES) uu = 0;                            \
        T[j] = hs_in[(size_t)uu * 64 + lane];                           \
    }

#define ACCUM(T)                                                        \
    _Pragma("unroll")                                                   \
    for (int j = 0; j < 16; ++j) {                                      \
        while (ecur == bound) {                                         \
            sAgg[wavei][cur - vbase][lane] =                            \
                (_Float16)(acc * norm_dst[cur]);                        \
            acc = 0.0f;                                                 \
            ++cur;                                                      \
            bound = (cur < vend) ? row_start[cur + 1] : 0x7fffffff;     \
        }                                                               \
        acc += fp8_to_f(T[j]);                                          \
        ++ecur;                                                         \
    }

__global__ __launch_bounds__(256) void conv64_kernel(
        const unsigned char* __restrict__ hs_in,
        const int* __restrict__ row_start,
        const int* __restrict__ csr_src,
        const float* __restrict__ norm_src,
        const float* __restrict__ norm_dst,
        const _Float16* __restrict__ WT, const float* __restrict__ b,
        unsigned char* __restrict__ out8,
        const int* __restrict__ graph_ids, float* __restrict__ gacc,
        int do_pool, int N) {
    __shared__ _Float16 sAgg[4][16][72];
    const int lane = threadIdx.x & 63;
    const int wavei = __builtin_amdgcn_readfirstlane(threadIdx.x >> 6);
    const int vbase = blockIdx.x * 32 + wavei * 8;
    if (vbase >= N) return;                       // no barriers => safe

    const int vend = min(vbase + 8, N);
    const int rs = row_start[vbase];
    const int re = row_start[vend];
    int cur = vbase;
    int bound = row_start[vbase + 1];
    int ecur = rs;
    float acc = 0.0f;
    int nbp = (re - rs + 15) >> 4;
    int e = rs;
    int idxA[16], idxB[16];
    unsigned char tA[16], tB[16];

    if (nbp > 0) {
        LOADIDX(idxA, e);
        GATHER(tA, idxA);
        LOADIDX(idxB, e + 16);
        int k = 0;
        while (k + 2 <= nbp) {
            GATHER(tB, idxB);
            LOADIDX(idxA, e + 32);
            ACCUM(tA);
            if (k + 2 < nbp) {
                GATHER(tA, idxA);
                LOADIDX(idxB, e + 48);
            }
            ACCUM(tB);
            k += 2; e += 32;
        }
        if (k < nbp) { ACCUM(tA); }
    }
    while (cur < vend) {
        sAgg[wavei][cur - vbase][lane] = (_Float16)(acc * norm_dst[cur]);
        acc = 0.0f;
        ++cur;
    }

    const int l15 = lane & 15;
    const int quad = lane >> 4;
    const _Float16* aRow = &sAgg[wavei][l15][quad * 8];
    half8 a0 = *(const half8*)(aRow);
    half8 a1 = *(const half8*)(aRow + 32);

    floatx4 c[4];
#pragma unroll
    for (int nt = 0; nt < 4; ++nt) c[nt] = (floatx4){0.f, 0.f, 0.f, 0.f};

#pragma unroll
    for (int nt = 0; nt < 4; ++nt) {
        const _Float16* bp = WT + ((size_t)(nt * 16 + l15)) * 64 + quad * 8;
        half8 b0 = *(const half8*)bp;
        half8 b1 = *(const half8*)(bp + 32);
        c[nt] = __builtin_amdgcn_mfma_f32_16x16x32_f16(a0, b0, c[nt], 0, 0, 0);
        c[nt] = __builtin_amdgcn_mfma_f32_16x16x32_f16(a1, b1, c[nt], 0, 0, 0);
    }

    if (do_pool) {
        // N % 8 == 0 => all 8 rows valid here.
        int g0 = graph_ids[vbase];                 // wave-uniform s_loads
        int g7 = graph_ids[vbase + 7];
        if (g0 == g7) {
            // fast path: whole wave-group in one graph
#pragma unroll
            for (int nt = 0; nt < 4; ++nt) {
                float bias = b[nt * 16 + l15];
                float fsum = 0.0f;
                if (quad < 2) {
#pragma unroll
                    for (int r = 0; r < 4; ++r)
                        fsum += fmaxf(c[nt][r] + bias, 0.0f);
                }
                fsum += __shfl_xor(fsum, 16);      // quad0 + quad1
                if (quad == 0)
                    atomicAdd(&gacc[g0 * 64 + nt * 16 + l15], fsum);
            }
        } else {
            // graph boundary (~1% of waves): per-node atomics
#pragma unroll
            for (int nt = 0; nt < 4; ++nt) {
                float bias = b[nt * 16 + l15];
#pragma unroll
                for (int r = 0; r < 4; ++r) {
                    int m = quad * 4 + r;
                    if (m < 8) {
                        int v = vbase + m;
                        float val = fmaxf(c[nt][r] + bias, 0.0f);
                        atomicAdd(&gacc[graph_ids[v] * 64 + nt * 16 + l15], val);
                    }
                }
            }
        }
    } else {
#pragma unroll
        for (int nt = 0; nt < 4; ++nt) {
            float bias = b[nt * 16 + l15];
#pragma unroll
            for (int r = 0; r < 4; ++r) {
                int m = quad * 4 + r;
                int v = vbase + m;
                if (m < 8 && v < N) {
                    float val = fmaxf(c[nt][r] + bias, 0.0f) * norm_src[v];
                    out8[(size_t)v * 64 + nt * 16 + l15] = f_to_fp8(val);
                }
            }
        }
    }
}

// ---------------------------------------------------------------------------
// Pool stage 2: one wave per graph (16 blocks x 4 waves).
// ---------------------------------------------------------------------------
__global__ void pool2_kernel(const float* __restrict__ gacc, const float* __restrict__ gcnt,
                             const float* __restrict__ Wout, const float* __restrict__ bout,
                             float* __restrict__ out) {
    int lane = threadIdx.x & 63;
    int g = blockIdx.x * 4 + (threadIdx.x >> 6);   // 64 waves total
    float p = (gacc[g * 64 + lane] / gcnt[g]) * Wout[lane];
#pragma unroll
    for (int off = 32; off; off >>= 1) p += __shfl_xor(p, off);
    if (lane == 0) out[g] = 1.0f / (1.0f + expf(-(p + bout[0])));
}

// ---------------------------------------------------------------------------
extern "C" void kernel_launch(void* const* d_in, const int* in_sizes, int n_in,
                              void* d_out, int out_size, void* d_ws, size_t ws_size,
                              hipStream_t stream) {
    const int* src = (const int*)d_in[0];
    const int* dst = (const int*)d_in[1];
    const int* graph_ids = (const int*)d_in[2];
    const float* W1 = (const float*)d_in[3];
    const float* b1 = (const float*)d_in[4];
    const float* W2 = (const float*)d_in[5];
    const float* b2 = (const float*)d_in[6];
    const float* W3 = (const float*)d_in[7];
    const float* b3 = (const float*)d_in[8];
    const float* W4 = (const float*)d_in[9];
    const float* b4 = (const float*)d_in[10];
    const float* Wout = (const float*)d_in[11];
    const float* bout = (const float*)d_in[12];
    float* out = (float*)d_out;

    const int N = N_NODES, E = N_EDGES;

    unsigned char* buf8A = (unsigned char*)d_ws;           // N*64 fp8
    unsigned char* buf8B = buf8A + (size_t)N * 64;         // N*64 fp8
    _Float16* WT   = (_Float16*)(buf8B + (size_t)N * 64);  // 3*4096 f16
    float* gacc = (float*)(WT + 3 * 4096);                 // 64*64 f32
    float* gcnt = gacc + 64 * 64;                          // 64 f32
    unsigned char* hs0 = (unsigned char*)(gcnt + 64);      // N*4 fp8 (4B-aligned)
    float* norm_src = (float*)(hs0 + (size_t)N * 4);       // N
    float* norm_dst = norm_src + N;                        // N
    int* csr_src   = (int*)(norm_dst + N);                 // E
    int* row_start = csr_src + E;                          // N+1
    int* blk_sums  = row_start + (N + 1);                  // NB
    unsigned char* inpart  = (unsigned char*)(blk_sums + NB + 1);    // NS*N u8
    unsigned char* outpart = inpart + (size_t)NS * N;                // NS*N u8
    unsigned char* rank    = outpart + (size_t)NS * N;               // E u8

    // hist (512) + WT transpose (48) + gacc/gcnt zero (1)
    hist_wt_kernel<<<NP * NS + 49, 256, 0, stream>>>(src, dst, inpart, outpart, rank,
                                                     W2, W3, W4, WT, gacc);
    scan_block_feat_kernel<<<NB, 256, 0, stream>>>(inpart, outpart, graph_ids,
                                                   row_start, blk_sums,
                                                   norm_src, norm_dst, (uchar4*)hs0, gcnt, N);
    row_add_kernel<<<NB, 256, 0, stream>>>(row_start, blk_sums, N);
    csr_fill_kernel<<<(E / 4 + 255) / 256, 256, 0, stream>>>(src, dst, row_start, inpart,
                                                             rank, csr_src);

    conv4_kernel<<<(N + 3) / 4, 256, 0, stream>>>((const uchar4*)hs0, row_start, csr_src,
                                                  norm_src, norm_dst, W1, b1, buf8A, N);
    const int CB = (N + 31) / 32;   // 256 threads = 4 waves x 8 nodes
    conv64_kernel<<<CB, 256, 0, stream>>>(buf8A, row_start, csr_src, norm_src, norm_dst,
                                          WT + 0 * 4096, b2, buf8B, graph_ids, gacc, 0, N);
    conv64_kernel<<<CB, 256, 0, stream>>>(buf8B, row_start, csr_src, norm_src, norm_dst,
                                          WT + 1 * 4096, b3, buf8A, graph_ids, gacc, 0, N);
    conv64_kernel<<<CB, 256, 0, stream>>>(buf8A, row_start, csr_src, norm_src, norm_dst,
                                          WT + 2 * 4096, b4, (unsigned char*)nullptr,
                                          graph_ids, gacc, 1, N);

    pool2_kernel<<<16, 256, 0, stream>>>(gacc, gcnt, Wout, bout, out);
}